// Round 13
// baseline (274.342 us; speedup 1.0000x reference)
//
#include <hip/hip_runtime.h>

#define NF 128    // feature dim (in == out == 128)

// ---- bucketed CSR build (fine buckets, packed pairs) ----
#define BSHIFT 7                 // 128 nodes per bucket
#define BNODES (1 << BSHIFT)
#define NBUCK 782                // ceil(100000/128)
#define BCAP 2560                // edges per bucket region; mean 2048, sigma ~45 -> +11 sigma
#define CHUNK 4096               // edges per bucketize block (391 blocks; best measured cfg)
#define BZT 512                  // bucketize threads: 8 waves/block for latency hiding

typedef __attribute__((ext_vector_type(8))) short bf16x8;
typedef __attribute__((ext_vector_type(4))) float f32x4;

__device__ inline short f2bf_rne(float f) {
    unsigned u = __float_as_uint(f);
    u += 0x7FFFu + ((u >> 16) & 1u);  // round-to-nearest-even (inputs finite)
    return (short)(u >> 16);
}
__device__ inline float bf_lo(unsigned u) { return __uint_as_float(u << 16); }
__device__ inline float bf_hi(unsigned u) { return __uint_as_float(u & 0xFFFF0000u); }

// ============ prep: bcursor init + W -> bf16 in MFMA-fragment order ============
__global__ __launch_bounds__(256) void prep_kernel(const float* __restrict__ W,
                                                   unsigned short* __restrict__ wswz,
                                                   int* __restrict__ bcursor) {
    int t = blockIdx.x * 256 + threadIdx.x;
    if (t < NBUCK) bcursor[t] = t * BCAP;
    if (t < 2048) {
        int lane = t & 63, frag = t >> 6;
        int nb = frag & 7, kc = frag >> 3;
        int o = nb * 16 + (lane & 15);
        int k0 = kc * 32 + (lane >> 4) * 8;
        const float4* ap = (const float4*)(W + o * NF + k0);
        float4 a0 = ap[0], a1 = ap[1];
        bf16x8 v;
        v[0] = f2bf_rne(a0.x); v[1] = f2bf_rne(a0.y);
        v[2] = f2bf_rne(a0.z); v[3] = f2bf_rne(a0.w);
        v[4] = f2bf_rne(a1.x); v[5] = f2bf_rne(a1.y);
        v[6] = f2bf_rne(a1.z); v[7] = f2bf_rne(a1.w);
        *(bf16x8*)(wswz + (size_t)t * 8) = v;
    }
}

// ============ pass 1: bucketize + degree count ============
// 512 threads (8 waves), int4-vectorized. Also fire-and-forget atomicAdd on cnt[col]
// (in-degree) so gemm can derive dis without a separate CSR pass.
__global__ __launch_bounds__(BZT) void bucketize_kernel(const int* __restrict__ row,
                                                        const int* __restrict__ col,
                                                        int* __restrict__ bcursor,
                                                        int* __restrict__ bpacked,
                                                        int* __restrict__ cnt, int E) {
    __shared__ int2 pe[CHUNK];    // 32 KB
    __shared__ int hist[NBUCK];   // 3.1 KB
    __shared__ int base[NBUCK];   // 3.1 KB
    const int t = threadIdx.x;
    const int e0 = blockIdx.x * CHUNK;
    const int c_n = min(CHUNK, E - e0);
    const int c4 = c_n & ~3;
    for (int i = t; i < NBUCK; i += BZT) hist[i] = 0;
    __syncthreads();
    // load + stage + LDS histogram + global degree atomics, 4 edges per thread-iter
    for (int i = t * 4; i < c4; i += BZT * 4) {
        int4 cc = *(const int4*)(col + e0 + i);
        int4 rr = *(const int4*)(row + e0 + i);
        pe[i + 0] = make_int2(cc.x, rr.x);
        pe[i + 1] = make_int2(cc.y, rr.y);
        pe[i + 2] = make_int2(cc.z, rr.z);
        pe[i + 3] = make_int2(cc.w, rr.w);
        atomicAdd(&hist[cc.x >> BSHIFT], 1);
        atomicAdd(&hist[cc.y >> BSHIFT], 1);
        atomicAdd(&hist[cc.z >> BSHIFT], 1);
        atomicAdd(&hist[cc.w >> BSHIFT], 1);
        atomicAdd(&cnt[cc.x], 1);
        atomicAdd(&cnt[cc.y], 1);
        atomicAdd(&cnt[cc.z], 1);
        atomicAdd(&cnt[cc.w], 1);
    }
    for (int i = c4 + t; i < c_n; i += BZT) {
        int c = col[e0 + i];
        pe[i] = make_int2(c, row[e0 + i]);
        atomicAdd(&hist[c >> BSHIFT], 1);
        atomicAdd(&cnt[c], 1);
    }
    __syncthreads();
    for (int i = t; i < NBUCK; i += BZT) {
        int h = hist[i];
        base[i] = h ? atomicAdd(&bcursor[i], h) : 0;
        hist[i] = 0;  // reuse as local cursor
    }
    __syncthreads();
    // scatter, 4 edges per thread-iter (LDS b128 reads)
    for (int i = t * 4; i < c4; i += BZT * 4) {
        int4 a = *(const int4*)(&pe[i]);      // (c0,r0,c1,r1)
        int4 b = *(const int4*)(&pe[i + 2]);  // (c2,r2,c3,r3)
        int bk, pos;
        bk = a.x >> BSHIFT; pos = base[bk] + atomicAdd(&hist[bk], 1);
        bpacked[pos] = (a.y << BSHIFT) | (a.x & (BNODES - 1));
        bk = a.z >> BSHIFT; pos = base[bk] + atomicAdd(&hist[bk], 1);
        bpacked[pos] = (a.w << BSHIFT) | (a.z & (BNODES - 1));
        bk = b.x >> BSHIFT; pos = base[bk] + atomicAdd(&hist[bk], 1);
        bpacked[pos] = (b.y << BSHIFT) | (b.x & (BNODES - 1));
        bk = b.z >> BSHIFT; pos = base[bk] + atomicAdd(&hist[bk], 1);
        bpacked[pos] = (b.w << BSHIFT) | (b.z & (BNODES - 1));
    }
    for (int i = c4 + t; i < c_n; i += BZT) {
        int2 p = pe[i];
        int bk = p.x >> BSHIFT;
        int pos = base[bk] + atomicAdd(&hist[bk], 1);
        bpacked[pos] = (p.y << BSHIFT) | (p.x & (BNODES - 1));
    }
}

// ================= block exclusive scan helper =================
__device__ inline int block_exclusive_scan_256(int val) {
    __shared__ int wsum[4];
    int lane = threadIdx.x & 63, wave = threadIdx.x >> 6;
    int x = val;
#pragma unroll
    for (int off = 1; off < 64; off <<= 1) {
        int y = __shfl_up(x, off, 64);
        if (lane >= off) x += y;
    }
    if (lane == 63) wsum[wave] = x;
    __syncthreads();
    if (threadIdx.x == 0) {
        int acc = 0;
        for (int w = 0; w < 4; ++w) { int t = wsum[w]; wsum[w] = acc; acc += t; }
    }
    __syncthreads();
    return x - val + wsum[wave];
}

// ================= xws = (x @ W^T) * rsqrt(deg+1), stored bf16 =================
// (round-8 best structure; dis computed inline from cnt)
__global__ __launch_bounds__(256) void gemm_xws_kernel(const float* __restrict__ x,
                                                       const unsigned short* __restrict__ wswz,
                                                       const int* __restrict__ cnt,
                                                       unsigned short* __restrict__ xws,
                                                       int n) {
    __shared__ short Wl[NF * NF];  // 32768 B, fragment-order

    for (int i = threadIdx.x; i < NF * NF / 8; i += 256)
        *(bf16x8*)(&Wl[i * 8]) = *(const bf16x8*)(wswz + (size_t)i * 8);
    __syncthreads();

    const int lane = threadIdx.x & 63;
    const int wave = threadIdx.x >> 6;
    const int l15 = lane & 15;
    const int quad = lane >> 4;
    const int tile = blockIdx.x * 64;

    int r = tile + wave * 16 + l15;
    if (r >= n) r = n - 1;  // clamp: duplicate row, stores masked below

    // hoist all x loads (8 float4 in flight)
    float4 xa[4][2];
#pragma unroll
    for (int kc = 0; kc < 4; ++kc) {
        const float4* ap = (const float4*)(x + (size_t)r * NF + kc * 32 + quad * 8);
        xa[kc][0] = ap[0];
        xa[kc][1] = ap[1];
    }

    f32x4 acc[8];
#pragma unroll
    for (int nb = 0; nb < 8; ++nb) acc[nb] = (f32x4)0.0f;

#pragma unroll
    for (int kc = 0; kc < 4; ++kc) {
        bf16x8 Af;
        Af[0] = f2bf_rne(xa[kc][0].x); Af[1] = f2bf_rne(xa[kc][0].y);
        Af[2] = f2bf_rne(xa[kc][0].z); Af[3] = f2bf_rne(xa[kc][0].w);
        Af[4] = f2bf_rne(xa[kc][1].x); Af[5] = f2bf_rne(xa[kc][1].y);
        Af[6] = f2bf_rne(xa[kc][1].z); Af[7] = f2bf_rne(xa[kc][1].w);
#pragma unroll
        for (int nb = 0; nb < 8; ++nb) {
            bf16x8 Bf = *(const bf16x8*)(&Wl[((kc * 8 + nb) * 64 + lane) * 8]);
            acc[nb] = __builtin_amdgcn_mfma_f32_16x16x32_bf16(Af, Bf, acc[nb], 0, 0, 0);
        }
    }

    int rbase = tile + wave * 16 + quad * 4;
#pragma unroll
    for (int reg = 0; reg < 4; ++reg) {
        int rr = rbase + reg;
        if (rr < n) {
            float dsc = rsqrtf((float)cnt[rr] + 1.0f);
#pragma unroll
            for (int nb = 0; nb < 8; ++nb)
                xws[(size_t)rr * NF + nb * 16 + l15] = (unsigned short)f2bf_rne(acc[nb][reg] * dsc);
        }
    }
}

// ============ fused bucket CSR-build + gather ============
// One block per bucket: stage bpacked -> LDS hist -> scan -> scatter into LDS edl
// (bucket_build's work, no global CSR), then 4 waves gather the 128 nodes from edl.
// out[c] = rsqrt(deg_c+1) * (sum_src xws[src] + xws[c]) + b
__global__ __launch_bounds__(256) void bucket_gather_kernel(const int* __restrict__ bpacked,
                                                            const int* __restrict__ bcursor,
                                                            const int* __restrict__ cnt,
                                                            const unsigned short* __restrict__ xws,
                                                            const float* __restrict__ b,
                                                            float* __restrict__ out, int N) {
    __shared__ int pe[BCAP];     // 10240 B (packed)
    __shared__ int h[BNODES];    // 512 B: histogram -> cursor -> end offset
    __shared__ int offl[BNODES]; // 512 B: local start offset
    __shared__ int edl[BCAP];    // 10240 B: bucket-local CSR edge targets
    const int bkt = blockIdx.x;
    const int node0 = bkt << BSHIFT;
    const int nn = min(BNODES, N - node0);
    const int start = bkt * BCAP;
    const int ecnt = bcursor[bkt] - start;
    const int t = threadIdx.x;

    for (int i = t; i < nn; i += 256) h[i] = 0;
    __syncthreads();
    for (int i = t; i < ecnt; i += 256) {
        int p = bpacked[start + i];
        pe[i] = p;
        atomicAdd(&h[p & (BNODES - 1)], 1);
    }
    __syncthreads();
    int v0 = (2 * t < nn) ? h[2 * t] : 0;
    int v1 = (2 * t + 1 < nn) ? h[2 * t + 1] : 0;
    int exc = block_exclusive_scan_256(v0 + v1);  // contains barriers after h reads
    if (2 * t < nn) { offl[2 * t] = exc; h[2 * t] = exc; }
    if (2 * t + 1 < nn) { offl[2 * t + 1] = exc + v0; h[2 * t + 1] = exc + v0; }
    __syncthreads();
    for (int i = t; i < ecnt; i += 256) {
        int p = pe[i];
        int pos = atomicAdd(&h[p & (BNODES - 1)], 1);
        edl[pos] = p >> BSHIFT;
    }
    __syncthreads();
    // ---- gather phase: 4 waves, wave w handles nodes w, w+4, w+8, ... ----
    const int lane = t & 63;
    const int wid = t >> 6;
    const int lsub = lane & 31;
    const bool lo = lane < 32;

    for (int nl = wid; nl < nn; nl += 4) {
        const int node = node0 + nl;
        const int st = offl[nl];
        const int en = h[nl];           // cursor ended at start+count
        const float dc = rsqrtf((float)(en - st) + 1.0f);

        float ax = 0.f, ay = 0.f, az = 0.f, aw = 0.f;
        {
            uint2 u = *(const uint2*)(xws + (size_t)node * NF + lsub * 4);
            if (lo) { ax = bf_lo(u.x); ay = bf_hi(u.x); az = bf_lo(u.y); aw = bf_hi(u.y); }
        }
        int i = st;
        for (; i + 16 <= en; i += 16) {
            int r0 = edl[i], r1 = edl[i + 1], r2 = edl[i + 2], r3 = edl[i + 3];
            int r4 = edl[i + 4], r5 = edl[i + 5], r6 = edl[i + 6], r7 = edl[i + 7];
            int r8 = edl[i + 8], r9 = edl[i + 9], ra = edl[i + 10], rb = edl[i + 11];
            int rc = edl[i + 12], rd = edl[i + 13], re = edl[i + 14], rf = edl[i + 15];
            int sa = lo ? r0 : r1, sb = lo ? r2 : r3, sc = lo ? r4 : r5, sd = lo ? r6 : r7;
            int se = lo ? r8 : r9, sf = lo ? ra : rb, sg = lo ? rc : rd, sh = lo ? re : rf;
            uint2 ua = *(const uint2*)(xws + (size_t)sa * NF + lsub * 4);
            uint2 ub = *(const uint2*)(xws + (size_t)sb * NF + lsub * 4);
            uint2 uc = *(const uint2*)(xws + (size_t)sc * NF + lsub * 4);
            uint2 ud = *(const uint2*)(xws + (size_t)sd * NF + lsub * 4);
            uint2 ue = *(const uint2*)(xws + (size_t)se * NF + lsub * 4);
            uint2 uf = *(const uint2*)(xws + (size_t)sf * NF + lsub * 4);
            uint2 ug = *(const uint2*)(xws + (size_t)sg * NF + lsub * 4);
            uint2 uh = *(const uint2*)(xws + (size_t)sh * NF + lsub * 4);
            ax += bf_lo(ua.x) + bf_lo(ub.x) + bf_lo(uc.x) + bf_lo(ud.x);
            ay += bf_hi(ua.x) + bf_hi(ub.x) + bf_hi(uc.x) + bf_hi(ud.x);
            az += bf_lo(ua.y) + bf_lo(ub.y) + bf_lo(uc.y) + bf_lo(ud.y);
            aw += bf_hi(ua.y) + bf_hi(ub.y) + bf_hi(uc.y) + bf_hi(ud.y);
            ax += bf_lo(ue.x) + bf_lo(uf.x) + bf_lo(ug.x) + bf_lo(uh.x);
            ay += bf_hi(ue.x) + bf_hi(uf.x) + bf_hi(ug.x) + bf_hi(uh.x);
            az += bf_lo(ue.y) + bf_lo(uf.y) + bf_lo(ug.y) + bf_lo(uh.y);
            aw += bf_hi(ue.y) + bf_hi(uf.y) + bf_hi(ug.y) + bf_hi(uh.y);
        }
        for (; i < en; i += 8) {
            int i1 = min(i + 1, en - 1), i2 = min(i + 2, en - 1), i3 = min(i + 3, en - 1);
            int i4 = min(i + 4, en - 1), i5 = min(i + 5, en - 1), i6 = min(i + 6, en - 1),
                i7 = min(i + 7, en - 1);
            int r0 = edl[i], r1 = edl[i1], r2 = edl[i2], r3 = edl[i3];
            int r4 = edl[i4], r5 = edl[i5], r6 = edl[i6], r7 = edl[i7];
            int sa = lo ? r0 : r1, sb = lo ? r2 : r3, sc = lo ? r4 : r5, sd = lo ? r6 : r7;
            uint2 ua = *(const uint2*)(xws + (size_t)sa * NF + lsub * 4);
            uint2 ub = *(const uint2*)(xws + (size_t)sb * NF + lsub * 4);
            uint2 uc = *(const uint2*)(xws + (size_t)sc * NF + lsub * 4);
            uint2 ud = *(const uint2*)(xws + (size_t)sd * NF + lsub * 4);
            const int my0 = lo ? 0 : 1;
            if (i + my0 < en)     { ax += bf_lo(ua.x); ay += bf_hi(ua.x); az += bf_lo(ua.y); aw += bf_hi(ua.y); }
            if (i + 2 + my0 < en) { ax += bf_lo(ub.x); ay += bf_hi(ub.x); az += bf_lo(ub.y); aw += bf_hi(ub.y); }
            if (i + 4 + my0 < en) { ax += bf_lo(uc.x); ay += bf_hi(uc.x); az += bf_lo(uc.y); aw += bf_hi(uc.y); }
            if (i + 6 + my0 < en) { ax += bf_lo(ud.x); ay += bf_hi(ud.x); az += bf_lo(ud.y); aw += bf_hi(ud.y); }
        }
        ax += __shfl_xor(ax, 32, 64);
        ay += __shfl_xor(ay, 32, 64);
        az += __shfl_xor(az, 32, 64);
        aw += __shfl_xor(aw, 32, 64);
        if (lo) {
            float4 bb = ((const float4*)b)[lsub];
            float4 o;
            o.x = fmaf(ax, dc, bb.x);
            o.y = fmaf(ay, dc, bb.y);
            o.z = fmaf(az, dc, bb.z);
            o.w = fmaf(aw, dc, bb.w);
            ((float4*)(out + (size_t)node * NF))[lsub] = o;
        }
    }
}

extern "C" void kernel_launch(void* const* d_in, const int* in_sizes, int n_in,
                              void* d_out, int out_size, void* d_ws, size_t ws_size,
                              hipStream_t stream) {
    const float* x = (const float*)d_in[0];
    const int* ei = (const int*)d_in[1];
    const float* W = (const float*)d_in[2];
    const float* b = (const float*)d_in[3];
    float* out = (float*)d_out;

    const int N = in_sizes[0] / NF;
    const int E = in_sizes[1] / 2;
    const int* row = ei;      // sources
    const int* col = ei + E;  // targets

    // workspace: xws [N*128 bf16] | cnt [N] | wswz [16384 bf16] |
    //            bpacked [NBUCK*BCAP int] | bcursor [1024]
    char* ws = (char*)d_ws;
    unsigned short* xws = (unsigned short*)ws;
    ws += (size_t)N * NF * sizeof(unsigned short);
    int* cnt = (int*)ws; ws += (size_t)N * sizeof(int);
    unsigned short* wswz = (unsigned short*)ws; ws += (size_t)NF * NF * sizeof(unsigned short);
    int* bpacked = (int*)ws; ws += (size_t)NBUCK * BCAP * sizeof(int);
    int* bcursor = (int*)ws;

    const int CB = (E + CHUNK - 1) / CHUNK;

    // 0) zero degree counters
    hipMemsetAsync(cnt, 0, (size_t)N * sizeof(int), stream);

    // 1) prep (bcursor init + W swizzle/convert), then bucketize (+degree atomics)
    prep_kernel<<<8, 256, 0, stream>>>(W, wswz, bcursor);
    bucketize_kernel<<<CB, BZT, 0, stream>>>(row, col, bcursor, bpacked, cnt, E);

    // 2) xws = (x @ W^T) * rsqrt(deg+1)  (bf16), MFMA with swizzled W
    gemm_xws_kernel<<<(N + 63) / 64, 256, 0, stream>>>(x, wswz, cnt, xws, N);

    // 3) fused per-bucket CSR build + gather + self loop + bias
    bucket_gather_kernel<<<NBUCK, 256, 0, stream>>>(bpacked, bcursor, cnt, xws, b, out, N);
}

// Round 14
// 203.449 us; speedup vs baseline: 1.3485x; 1.3485x over previous
//
#include <hip/hip_runtime.h>

#define NF 128    // feature dim (in == out == 128)

// ---- bucketed CSR build (fine buckets, packed pairs) ----
#define BSHIFT 7                 // 128 nodes per bucket
#define BNODES (1 << BSHIFT)
#define NBUCK 782                // ceil(100000/128)
#define BCAP 2560                // edges per bucket region; mean 2048, sigma ~45 -> +11 sigma
#define CHUNK 4096               // edges per bucketize block (391 blocks; best measured cfg)
#define BZT 512                  // bucketize threads: 8 waves/block for latency hiding

typedef __attribute__((ext_vector_type(8))) short bf16x8;
typedef __attribute__((ext_vector_type(4))) float f32x4;

__device__ inline short f2bf_rne(float f) {
    unsigned u = __float_as_uint(f);
    u += 0x7FFFu + ((u >> 16) & 1u);  // round-to-nearest-even (inputs finite)
    return (short)(u >> 16);
}
__device__ inline float bf_lo(unsigned u) { return __uint_as_float(u << 16); }
__device__ inline float bf_hi(unsigned u) { return __uint_as_float(u & 0xFFFF0000u); }

// ============ prep: bcursor init + W -> bf16 in MFMA-fragment order ============
__global__ __launch_bounds__(256) void prep_kernel(const float* __restrict__ W,
                                                   unsigned short* __restrict__ wswz,
                                                   int* __restrict__ bcursor) {
    int t = blockIdx.x * 256 + threadIdx.x;
    if (t < NBUCK) bcursor[t] = t * BCAP;
    if (t < 2048) {
        int lane = t & 63, frag = t >> 6;
        int nb = frag & 7, kc = frag >> 3;
        int o = nb * 16 + (lane & 15);
        int k0 = kc * 32 + (lane >> 4) * 8;
        const float4* ap = (const float4*)(W + o * NF + k0);
        float4 a0 = ap[0], a1 = ap[1];
        bf16x8 v;
        v[0] = f2bf_rne(a0.x); v[1] = f2bf_rne(a0.y);
        v[2] = f2bf_rne(a0.z); v[3] = f2bf_rne(a0.w);
        v[4] = f2bf_rne(a1.x); v[5] = f2bf_rne(a1.y);
        v[6] = f2bf_rne(a1.z); v[7] = f2bf_rne(a1.w);
        *(bf16x8*)(wswz + (size_t)t * 8) = v;
    }
}

// ============ pass 1: bucketize edges by col>>7, write PACKED (row<<7|col_local) ============
// 512 threads (8 waves) + int4-vectorized loads: each phase is ~2 wide iterations
// instead of 16 serial ones. LDS int2 staging (read col/row ONCE from global).
__global__ __launch_bounds__(BZT) void bucketize_kernel(const int* __restrict__ row,
                                                        const int* __restrict__ col,
                                                        int* __restrict__ bcursor,
                                                        int* __restrict__ bpacked, int E) {
    __shared__ int2 pe[CHUNK];    // 32 KB
    __shared__ int hist[NBUCK];   // 3.1 KB
    __shared__ int base[NBUCK];   // 3.1 KB
    const int t = threadIdx.x;
    const int e0 = blockIdx.x * CHUNK;
    const int cnt = min(CHUNK, E - e0);
    const int cnt4 = cnt & ~3;
    for (int i = t; i < NBUCK; i += BZT) hist[i] = 0;
    __syncthreads();
    // load + stage + histogram, 4 edges per thread-iter
    for (int i = t * 4; i < cnt4; i += BZT * 4) {
        int4 c4 = *(const int4*)(col + e0 + i);
        int4 r4 = *(const int4*)(row + e0 + i);
        pe[i + 0] = make_int2(c4.x, r4.x);
        pe[i + 1] = make_int2(c4.y, r4.y);
        pe[i + 2] = make_int2(c4.z, r4.z);
        pe[i + 3] = make_int2(c4.w, r4.w);
        atomicAdd(&hist[c4.x >> BSHIFT], 1);
        atomicAdd(&hist[c4.y >> BSHIFT], 1);
        atomicAdd(&hist[c4.z >> BSHIFT], 1);
        atomicAdd(&hist[c4.w >> BSHIFT], 1);
    }
    for (int i = cnt4 + t; i < cnt; i += BZT) {
        int c = col[e0 + i];
        pe[i] = make_int2(c, row[e0 + i]);
        atomicAdd(&hist[c >> BSHIFT], 1);
    }
    __syncthreads();
    for (int i = t; i < NBUCK; i += BZT) {
        int h = hist[i];
        base[i] = h ? atomicAdd(&bcursor[i], h) : 0;
        hist[i] = 0;  // reuse as local cursor
    }
    __syncthreads();
    // scatter, 4 edges per thread-iter (LDS b128 reads)
    for (int i = t * 4; i < cnt4; i += BZT * 4) {
        int4 a = *(const int4*)(&pe[i]);      // (c0,r0,c1,r1)
        int4 b = *(const int4*)(&pe[i + 2]);  // (c2,r2,c3,r3)
        int bk, pos;
        bk = a.x >> BSHIFT; pos = base[bk] + atomicAdd(&hist[bk], 1);
        bpacked[pos] = (a.y << BSHIFT) | (a.x & (BNODES - 1));
        bk = a.z >> BSHIFT; pos = base[bk] + atomicAdd(&hist[bk], 1);
        bpacked[pos] = (a.w << BSHIFT) | (a.z & (BNODES - 1));
        bk = b.x >> BSHIFT; pos = base[bk] + atomicAdd(&hist[bk], 1);
        bpacked[pos] = (b.y << BSHIFT) | (b.x & (BNODES - 1));
        bk = b.z >> BSHIFT; pos = base[bk] + atomicAdd(&hist[bk], 1);
        bpacked[pos] = (b.w << BSHIFT) | (b.z & (BNODES - 1));
    }
    for (int i = cnt4 + t; i < cnt; i += BZT) {
        int2 p = pe[i];
        int bk = p.x >> BSHIFT;
        int pos = base[bk] + atomicAdd(&hist[bk], 1);
        bpacked[pos] = (p.y << BSHIFT) | (p.x & (BNODES - 1));
    }
}

// ================= block exclusive scan helper =================
__device__ inline int block_exclusive_scan_256(int val) {
    __shared__ int wsum[4];
    int lane = threadIdx.x & 63, wave = threadIdx.x >> 6;
    int x = val;
#pragma unroll
    for (int off = 1; off < 64; off <<= 1) {
        int y = __shfl_up(x, off, 64);
        if (lane >= off) x += y;
    }
    if (lane == 63) wsum[wave] = x;
    __syncthreads();
    if (threadIdx.x == 0) {
        int acc = 0;
        for (int w = 0; w < 4; ++w) { int t = wsum[w]; wsum[w] = acc; acc += t; }
    }
    __syncthreads();
    return x - val + wsum[wave];
}

// ============ pass 2 (fused): per-bucket count + local scan + CSR fill ============
// LDS = 10 KB pe + 0.5 KB h + 10 KB edl ~= 21 KB -> 7 blocks/CU capacity.
__global__ __launch_bounds__(256) void bucket_build_kernel(const int* __restrict__ bpacked,
                                                           const int* __restrict__ bcursor,
                                                           int* __restrict__ cnt,
                                                           float* __restrict__ dis,
                                                           int* __restrict__ offs,
                                                           int* __restrict__ ed, int N) {
    __shared__ int pe[BCAP];    // 10240 B (packed)
    __shared__ int h[BNODES];   // 512 B: histogram, then local cursor
    __shared__ int edl[BCAP];   // 10240 B: ed assembled locally, streamed out coalesced
    const int b = blockIdx.x;
    const int node0 = b << BSHIFT;
    const int nn = min(BNODES, N - node0);
    const int start = b * BCAP;
    const int ecnt = bcursor[b] - start;
    for (int i = threadIdx.x; i < nn; i += 256) h[i] = 0;
    __syncthreads();
    for (int i = threadIdx.x; i < ecnt; i += 256) {
        int p = bpacked[start + i];
        pe[i] = p;
        atomicAdd(&h[p & (BNODES - 1)], 1);
    }
    __syncthreads();
    const int t = threadIdx.x;
    int v0 = (2 * t < nn) ? h[2 * t] : 0;
    int v1 = (2 * t + 1 < nn) ? h[2 * t + 1] : 0;
    int exc = block_exclusive_scan_256(v0 + v1);  // contains barriers after h reads
    if (2 * t < nn) {
        offs[node0 + 2 * t] = start + exc;
        cnt[node0 + 2 * t] = v0;
        dis[node0 + 2 * t] = rsqrtf((float)v0 + 1.0f);
        h[2 * t] = exc;         // local cursor
    }
    if (2 * t + 1 < nn) {
        offs[node0 + 2 * t + 1] = start + exc + v0;
        cnt[node0 + 2 * t + 1] = v1;
        dis[node0 + 2 * t + 1] = rsqrtf((float)v1 + 1.0f);
        h[2 * t + 1] = exc + v0;
    }
    __syncthreads();
    for (int i = threadIdx.x; i < ecnt; i += 256) {
        int p = pe[i];
        int pos = atomicAdd(&h[p & (BNODES - 1)], 1);
        edl[pos] = p >> BSHIFT;
    }
    __syncthreads();
    for (int i = threadIdx.x; i < ecnt; i += 256) ed[start + i] = edl[i];
}

// ================= xws = (x @ W^T) * dis[row], stored bf16 =================
// (round-8 best-measured version) MFMA 16x16x32 bf16. 64-row tile/block, one 16-row
// strip per wave. W staged from pre-swizzled wswz: linear 32 KB copy; B-fragment
// reads are base + lane*16B (zero bank conflicts). All 8 x-float4 loads hoisted.
__global__ __launch_bounds__(256) void gemm_xws_kernel(const float* __restrict__ x,
                                                       const unsigned short* __restrict__ wswz,
                                                       const float* __restrict__ dis,
                                                       unsigned short* __restrict__ xws,
                                                       int n) {
    __shared__ short Wl[NF * NF];  // 32768 B, fragment-order

    for (int i = threadIdx.x; i < NF * NF / 8; i += 256)
        *(bf16x8*)(&Wl[i * 8]) = *(const bf16x8*)(wswz + (size_t)i * 8);
    __syncthreads();

    const int lane = threadIdx.x & 63;
    const int wave = threadIdx.x >> 6;
    const int l15 = lane & 15;
    const int quad = lane >> 4;
    const int tile = blockIdx.x * 64;

    int r = tile + wave * 16 + l15;
    if (r >= n) r = n - 1;  // clamp: duplicate row, stores masked below

    // hoist all x loads (8 float4 in flight)
    float4 xa[4][2];
#pragma unroll
    for (int kc = 0; kc < 4; ++kc) {
        const float4* ap = (const float4*)(x + (size_t)r * NF + kc * 32 + quad * 8);
        xa[kc][0] = ap[0];
        xa[kc][1] = ap[1];
    }

    f32x4 acc[8];
#pragma unroll
    for (int nb = 0; nb < 8; ++nb) acc[nb] = (f32x4)0.0f;

#pragma unroll
    for (int kc = 0; kc < 4; ++kc) {
        bf16x8 Af;
        Af[0] = f2bf_rne(xa[kc][0].x); Af[1] = f2bf_rne(xa[kc][0].y);
        Af[2] = f2bf_rne(xa[kc][0].z); Af[3] = f2bf_rne(xa[kc][0].w);
        Af[4] = f2bf_rne(xa[kc][1].x); Af[5] = f2bf_rne(xa[kc][1].y);
        Af[6] = f2bf_rne(xa[kc][1].z); Af[7] = f2bf_rne(xa[kc][1].w);
#pragma unroll
        for (int nb = 0; nb < 8; ++nb) {
            bf16x8 Bf = *(const bf16x8*)(&Wl[((kc * 8 + nb) * 64 + lane) * 8]);
            acc[nb] = __builtin_amdgcn_mfma_f32_16x16x32_bf16(Af, Bf, acc[nb], 0, 0, 0);
        }
    }

    int rbase = tile + wave * 16 + quad * 4;
#pragma unroll
    for (int reg = 0; reg < 4; ++reg) {
        int rr = rbase + reg;
        if (rr < n) {
            float dsc = dis[rr];
#pragma unroll
            for (int nb = 0; nb < 8; ++nb)
                xws[(size_t)rr * NF + nb * 16 + l15] = (unsigned short)f2bf_rne(acc[nb][reg] * dsc);
        }
    }
}

// ================= gather: one wave per node, TWO rows per VMEM instr =================
// Lanes 0-31 read row A, lanes 32-63 read row B (8 B/lane); 16-edge main iter keeps
// 8 uint2 loads in flight. Tail: masked 8-wide (4 loads in flight, indices clamped,
// accumulation predicated).
// out[c] = dc * (sum_src xws[src] + xws[c]) + b
__global__ __launch_bounds__(256) void gather_kernel(const int* __restrict__ ed,
                                                     const int* __restrict__ offs,
                                                     const int* __restrict__ cnt,
                                                     const float* __restrict__ dis,
                                                     const unsigned short* __restrict__ xws,
                                                     const float* __restrict__ b,
                                                     float* __restrict__ out,
                                                     int nbase, int nend) {
    int node = nbase + (int)((blockIdx.x * blockDim.x + threadIdx.x) >> 6);
    const int lane = threadIdx.x & 63;
    if (node >= nend) return;
    node = __builtin_amdgcn_readfirstlane(node);  // pin scalar: ed/offs loads go SMEM
    const int lsub = lane & 31;
    const bool lo = lane < 32;
    const float dc = dis[node];
    const int start = offs[node];
    const int end = start + cnt[node];

    float ax = 0.f, ay = 0.f, az = 0.f, aw = 0.f;
    // self row: all lanes load (one 512B fetch), upper half discards
    {
        uint2 u = *(const uint2*)(xws + (size_t)node * NF + lsub * 4);
        if (lo) { ax = bf_lo(u.x); ay = bf_hi(u.x); az = bf_lo(u.y); aw = bf_hi(u.y); }
    }
    int i = start;
    for (; i + 16 <= end; i += 16) {
        int r0 = ed[i], r1 = ed[i + 1], r2 = ed[i + 2], r3 = ed[i + 3];
        int r4 = ed[i + 4], r5 = ed[i + 5], r6 = ed[i + 6], r7 = ed[i + 7];
        int r8 = ed[i + 8], r9 = ed[i + 9], ra = ed[i + 10], rb = ed[i + 11];
        int rc = ed[i + 12], rd = ed[i + 13], re = ed[i + 14], rf = ed[i + 15];
        int sa = lo ? r0 : r1, sb = lo ? r2 : r3, sc = lo ? r4 : r5, sd = lo ? r6 : r7;
        int se = lo ? r8 : r9, sf = lo ? ra : rb, sg = lo ? rc : rd, sh = lo ? re : rf;
        uint2 ua = *(const uint2*)(xws + (size_t)sa * NF + lsub * 4);
        uint2 ub = *(const uint2*)(xws + (size_t)sb * NF + lsub * 4);
        uint2 uc = *(const uint2*)(xws + (size_t)sc * NF + lsub * 4);
        uint2 ud = *(const uint2*)(xws + (size_t)sd * NF + lsub * 4);
        uint2 ue = *(const uint2*)(xws + (size_t)se * NF + lsub * 4);
        uint2 uf = *(const uint2*)(xws + (size_t)sf * NF + lsub * 4);
        uint2 ug = *(const uint2*)(xws + (size_t)sg * NF + lsub * 4);
        uint2 uh = *(const uint2*)(xws + (size_t)sh * NF + lsub * 4);
        ax += bf_lo(ua.x) + bf_lo(ub.x) + bf_lo(uc.x) + bf_lo(ud.x);
        ay += bf_hi(ua.x) + bf_hi(ub.x) + bf_hi(uc.x) + bf_hi(ud.x);
        az += bf_lo(ua.y) + bf_lo(ub.y) + bf_lo(uc.y) + bf_lo(ud.y);
        aw += bf_hi(ua.y) + bf_hi(ub.y) + bf_hi(uc.y) + bf_hi(ud.y);
        ax += bf_lo(ue.x) + bf_lo(uf.x) + bf_lo(ug.x) + bf_lo(uh.x);
        ay += bf_hi(ue.x) + bf_hi(uf.x) + bf_hi(ug.x) + bf_hi(uh.x);
        az += bf_lo(ue.y) + bf_lo(uf.y) + bf_lo(ug.y) + bf_lo(uh.y);
        aw += bf_hi(ue.y) + bf_hi(uf.y) + bf_hi(ug.y) + bf_hi(uh.y);
    }
    // masked 8-wide tail: indices clamped to end-1 (duplicate loads OK), adds predicated
    for (; i < end; i += 8) {
        int i1 = min(i + 1, end - 1), i2 = min(i + 2, end - 1), i3 = min(i + 3, end - 1);
        int i4 = min(i + 4, end - 1), i5 = min(i + 5, end - 1), i6 = min(i + 6, end - 1),
            i7 = min(i + 7, end - 1);
        int r0 = ed[i], r1 = ed[i1], r2 = ed[i2], r3 = ed[i3];
        int r4 = ed[i4], r5 = ed[i5], r6 = ed[i6], r7 = ed[i7];
        int sa = lo ? r0 : r1, sb = lo ? r2 : r3, sc = lo ? r4 : r5, sd = lo ? r6 : r7;
        uint2 ua = *(const uint2*)(xws + (size_t)sa * NF + lsub * 4);
        uint2 ub = *(const uint2*)(xws + (size_t)sb * NF + lsub * 4);
        uint2 uc = *(const uint2*)(xws + (size_t)sc * NF + lsub * 4);
        uint2 ud = *(const uint2*)(xws + (size_t)sd * NF + lsub * 4);
        const int my0 = lo ? 0 : 1;
        if (i + my0 < end)     { ax += bf_lo(ua.x); ay += bf_hi(ua.x); az += bf_lo(ua.y); aw += bf_hi(ua.y); }
        if (i + 2 + my0 < end) { ax += bf_lo(ub.x); ay += bf_hi(ub.x); az += bf_lo(ub.y); aw += bf_hi(ub.y); }
        if (i + 4 + my0 < end) { ax += bf_lo(uc.x); ay += bf_hi(uc.x); az += bf_lo(uc.y); aw += bf_hi(uc.y); }
        if (i + 6 + my0 < end) { ax += bf_lo(ud.x); ay += bf_hi(ud.x); az += bf_lo(ud.y); aw += bf_hi(ud.y); }
    }
    // combine the two half-wave accumulators
    ax += __shfl_xor(ax, 32, 64);
    ay += __shfl_xor(ay, 32, 64);
    az += __shfl_xor(az, 32, 64);
    aw += __shfl_xor(aw, 32, 64);
    if (lo) {
        float4 bb = ((const float4*)b)[lsub];
        float4 o;
        o.x = fmaf(ax, dc, bb.x);
        o.y = fmaf(ay, dc, bb.y);
        o.z = fmaf(az, dc, bb.z);
        o.w = fmaf(aw, dc, bb.w);
        ((float4*)(out + (size_t)node * NF))[lsub] = o;
    }
}

extern "C" void kernel_launch(void* const* d_in, const int* in_sizes, int n_in,
                              void* d_out, int out_size, void* d_ws, size_t ws_size,
                              hipStream_t stream) {
    const float* x = (const float*)d_in[0];
    const int* ei = (const int*)d_in[1];
    const float* W = (const float*)d_in[2];
    const float* b = (const float*)d_in[3];
    float* out = (float*)d_out;

    const int N = in_sizes[0] / NF;
    const int E = in_sizes[1] / 2;
    const int* row = ei;      // sources
    const int* col = ei + E;  // targets

    // workspace: xws [N*128 bf16] | cnt [N] | dis [N] | offs [N] | wswz [16384 bf16] |
    //            bpacked [NBUCK*BCAP int] | bcursor [1024] | ed [NBUCK*BCAP int]
    char* ws = (char*)d_ws;
    unsigned short* xws = (unsigned short*)ws;
    ws += (size_t)N * NF * sizeof(unsigned short);
    int* cnt = (int*)ws; ws += (size_t)N * sizeof(int);
    float* dis = (float*)ws; ws += (size_t)N * sizeof(float);
    int* offs = (int*)ws; ws += (size_t)N * sizeof(int);
    unsigned short* wswz = (unsigned short*)ws; ws += (size_t)NF * NF * sizeof(unsigned short);
    int* bpacked = (int*)ws; ws += (size_t)NBUCK * BCAP * sizeof(int);
    int* bcursor = (int*)ws; ws += 1024 * sizeof(int);
    int* ed = (int*)ws;

    const int CB = (E + CHUNK - 1) / CHUNK;

    // 1) prep (bcursor init + W swizzle/convert), then bucketize (8-wave, vectorized)
    prep_kernel<<<8, 256, 0, stream>>>(W, wswz, bcursor);
    bucketize_kernel<<<CB, BZT, 0, stream>>>(row, col, bcursor, bpacked, E);

    // 2) fused per-bucket count + local scan + CSR fill (bucket-padded ed)
    bucket_build_kernel<<<NBUCK, 256, 0, stream>>>(bpacked, bcursor, cnt, dis, offs, ed, N);

    // 3) xws = (x @ W^T) * dis[row]  (bf16), MFMA with swizzled W (round-8 best)
    gemm_xws_kernel<<<(N + 63) / 64, 256, 0, stream>>>(x, wswz, dis, xws, N);

    // 4) gather + self loop + bias (single dispatch: saves one launch + drain)
    {
        int blocks = (N + 3) / 4;
        gather_kernel<<<blocks, 256, 0, stream>>>(ed, offs, cnt, dis, xws, b, out, 0, N);
    }
}